// Round 5
// baseline (480.609 us; speedup 1.0000x reference)
//
#include <hip/hip_runtime.h>
#include <hip/hip_bf16.h>
#include <math.h>

// Problem constants (from reference)
#define T_TOK 8192            // B*S = 4*2048
#define HID   1024
#define NE    8
#define TOPKN 2
#define INTER 1408
#define NROWS (T_TOK*TOPKN)   // 16384 routed (token,expert) rows
#define MAXWL 144             // max row-block worklist entries (<=135 real)
#define RBLK  256             // router blocks (32 tokens each)
#define TPM   (NE * 44 * 32)  // transpose blocks per matrix = 11264

typedef __attribute__((ext_vector_type(8))) __bf16 bf16x8;
typedef __attribute__((ext_vector_type(4))) float f32x4;
typedef __attribute__((ext_vector_type(4))) unsigned int u32x4;

__device__ __forceinline__ unsigned short f2bf(float f) {
    unsigned int u = __builtin_bit_cast(unsigned int, f);
    unsigned int lsb = (u >> 16) & 1u;
    u += 0x7fffu + lsb;            // round-to-nearest-even
    return (unsigned short)(u >> 16);
}

// async global->LDS, 16B per lane (m97 pattern).
__device__ __forceinline__ void gl2lds16(const void* g, void* l) {
    __builtin_amdgcn_global_load_lds(
        (const __attribute__((address_space(1))) unsigned int*)g,
        (__attribute__((address_space(3))) unsigned int*)l, 16, 0, 0);
}

// ---------------------------------------------------------------- prep
// One kernel, whole chip busy: router (blocks 0..RBLK-1) + all 3 weight
// transposes (independent work, previously 4 serialized launches).
__global__ __launch_bounds__(256) void moe_prep(
    const float* __restrict__ x, const float* __restrict__ gate_w,
    const float* __restrict__ w_gate, const float* __restrict__ w_up,
    const float* __restrict__ w_down,
    unsigned short* __restrict__ xb, float* __restrict__ logits_out,
    int* __restrict__ topk_idx, float* __restrict__ topk_w,
    int* __restrict__ hist_g,
    unsigned short* __restrict__ wg_t, unsigned short* __restrict__ wu_t,
    unsigned short* __restrict__ wd_t)
{
    __shared__ float tile[32][33];
    __shared__ int lh[NE];
    int bid = blockIdx.x, tid = threadIdx.x;

    if (bid < RBLK) {
        // ---------------- router: 32 tokens, wave-per-token x8 ----------------
        int wave = tid >> 6, lane = tid & 63;
        if (tid < NE) lh[tid] = 0;
        __syncthreads();
#pragma unroll 1
        for (int i = 0; i < 8; i++) {
            int t = bid * 32 + wave * 8 + i;
            const float4* xr = (const float4*)(x + (size_t)t * HID);
            float acc[NE];
#pragma unroll
            for (int e = 0; e < NE; e++) acc[e] = 0.f;
#pragma unroll
            for (int j = 0; j < 4; j++) {
                float4 xv = xr[j * 64 + lane];
                ushort4 pk;
                pk.x = f2bf(xv.x); pk.y = f2bf(xv.y);
                pk.z = f2bf(xv.z); pk.w = f2bf(xv.w);
                *(ushort4*)(xb + (size_t)t * HID + j * 256 + lane * 4) = pk;
#pragma unroll
                for (int e = 0; e < NE; e++) {
                    float4 gv = *(const float4*)(gate_w + e * HID + j * 256 + lane * 4);
                    acc[e] += xv.x * gv.x + xv.y * gv.y + xv.z * gv.z + xv.w * gv.w;
                }
            }
#pragma unroll
            for (int e = 0; e < NE; e++) {
                float v = acc[e];
#pragma unroll
                for (int off = 32; off; off >>= 1) v += __shfl_xor(v, off, 64);
                acc[e] = v;
            }
            if (lane == 0) {
                float m = acc[0];
#pragma unroll
                for (int e = 1; e < NE; e++) m = fmaxf(m, acc[e]);
                float p[NE]; float s = 0.f;
#pragma unroll
                for (int e = 0; e < NE; e++) { p[e] = expf(acc[e] - m); s += p[e]; }
                float inv = 1.f / s;
#pragma unroll
                for (int e = 0; e < NE; e++) logits_out[(size_t)t * NE + e] = acc[e];
                int i0 = 0;
#pragma unroll
                for (int e = 1; e < NE; e++) if (p[e] > p[i0]) i0 = e;
                int i1 = (i0 == 0) ? 1 : 0;
#pragma unroll
                for (int e = 0; e < NE; e++) if (e != i0 && p[e] > p[i1]) i1 = e;
                topk_idx[2 * t]     = i0; topk_w[2 * t]     = p[i0] * inv;
                topk_idx[2 * t + 1] = i1; topk_w[2 * t + 1] = p[i1] * inv;
                atomicAdd(&lh[i0], 1);
                atomicAdd(&lh[i1], 1);
            }
        }
        __syncthreads();
        if (tid < NE) hist_g[bid * NE + tid] = lh[tid];
        return;
    }

    // ---------------- transpose+cast: fp32 [E][R][C] -> bf16 [E][C][R] ----------------
    int t = bid - RBLK;
    int mat = t / TPM, rem = t % TPM;
    int e = rem / (44 * 32), r2 = rem % (44 * 32);
    const float* in; unsigned short* outp; int R_, C_, cx, cy;
    if (mat < 2) {
        R_ = HID; C_ = INTER; cx = r2 % 44; cy = r2 / 44;
        in = mat ? w_up : w_gate; outp = mat ? wu_t : wg_t;
    } else {
        R_ = INTER; C_ = HID; cx = r2 % 32; cy = r2 / 32;
        in = w_down; outp = wd_t;
    }
    const float* ine = in + (size_t)e * R_ * C_;
    unsigned short* oute = outp + (size_t)e * R_ * C_;
    int c0 = cx * 32, r0 = cy * 32;
    int tx = tid & 31, ty = tid >> 5;   // (32,8)
#pragma unroll
    for (int j = 0; j < 4; j++) {
        int r = r0 + ty + j * 8;
        tile[ty + j * 8][tx] = ine[(size_t)r * C_ + c0 + tx];
    }
    __syncthreads();
#pragma unroll
    for (int j = 0; j < 4; j++) {
        int c = c0 + ty + j * 8;
        oute[(size_t)c * R_ + r0 + tx] = f2bf(tile[tx][ty + j * 8]);
    }
}

// ---------------------------------------------------------------- scatter+scan
// 256 blocks; each redundantly computes expert totals + its own bases from
// hist_g (2 KB) -> no single-block serial scan, no global atomics.
// Block 0 also emits offsets + sentinel-padded worklist.
__global__ __launch_bounds__(256) void moe_scatter_scan(
    const int* __restrict__ hist_g, const int* __restrict__ topk_idx,
    const float* __restrict__ topk_w,
    int* __restrict__ offsets, int* __restrict__ wl,
    int* __restrict__ row_token, float* __restrict__ row_w,
    int* __restrict__ tok_rows)
{
    __shared__ int h[RBLK * NE];
    __shared__ int base[NE], cnt[NE];
    int tid = threadIdx.x;
    for (int i = tid; i < RBLK * NE; i += 256) h[i] = hist_g[i];
    __syncthreads();
    if (tid < NE) {
        int b0 = blockIdx.x;
        int s = 0, bb = 0;
        for (int b = 0; b < RBLK; b++) {
            int v = h[b * NE + tid];
            s += v;
            if (b < b0) bb += v;
        }
        cnt[tid] = s;
        base[tid] = bb;   // partial: add expert offset below
    }
    __syncthreads();
    if (tid < NE) {
        int off = 0;
        for (int e = 0; e < tid; e++) off += cnt[e];
        base[tid] += off;
    }
    if (blockIdx.x == 0) {
        if (tid == 64) {
            int s = 0;
            for (int e = 0; e < NE; e++) { offsets[e] = s; s += cnt[e]; }
            offsets[NE] = s;
        }
        if (tid == 128) {
            int n = 0;
            for (int e = 0; e < NE; e++)
                for (int r0 = 0; r0 < cnt[e]; r0 += 128)
                    wl[n++] = (e << 24) | r0;
            while (n < MAXWL) wl[n++] = 0x00ffffff;  // sentinel: row0 >= any cnt
        }
    }
    __syncthreads();
    if (tid < 64) {
        int idx = blockIdx.x * 64 + tid;     // = 2*t + k
        int e = topk_idx[idx];
        int pos = atomicAdd(&base[e], 1);    // LDS atomic
        row_token[pos] = idx >> 1;
        row_w[pos] = topk_w[idx];
        tok_rows[idx] = pos;
    }
}

// ---------------------------------------------------------------- grouped GEMM1
// 128 rows x 64 i-cols per block, computes BOTH g and u (SiLU pairing wave-local).
// LDS row-major [row][chunk], chunk c of row r holds logical k-chunk q = c^(r&7)
// (XOR swizzle): staging lane-contiguous AND coalesced; frag reads 2-way (free).
__global__ __launch_bounds__(256) void moe_gemm1(
    const unsigned short* __restrict__ xb,
    const unsigned short* __restrict__ wg_t,   // [NE][INTER][HID]
    const unsigned short* __restrict__ wu_t,   // [NE][INTER][HID]
    const int* __restrict__ offsets, const int* __restrict__ row_token,
    const int* __restrict__ wl,
    unsigned short* __restrict__ h_buf)        // [NROWS][INTER]
{
    int wle = wl[blockIdx.y];
    int e = wle >> 24, row0 = wle & 0xffffff;
    int off = offsets[e], cnt = offsets[e + 1] - off;
    if (row0 >= cnt) return;
    int i0 = blockIdx.x * 64;

    __shared__ __align__(16) unsigned short As[128 * 64];  // 16 KB: [row][8 chunks]
    __shared__ __align__(16) unsigned short Bg[64 * 64];   // 8 KB
    __shared__ __align__(16) unsigned short Bu[64 * 64];   // 8 KB

    int tid = threadIdx.x, wave = tid >> 6, lane = tid & 63;
    int wm = wave & 1, wn = wave >> 1;
    int l16 = lane & 15, quad = lane >> 4;
    int r_ = lane >> 3, c_ = lane & 7;     // staging: 8 rows x 8 chunks per wave-instr
    int sw = l16 & 7;                      // frag-read xor swizzle

    const unsigned short* asrc[4];
#pragma unroll
    for (int it = 0; it < 4; it++) {
        int rloc = it * 32 + wave * 8 + r_;
        int rg = row0 + rloc;
        int tok = row_token[off + ((rg < cnt) ? rg : 0)];
        asrc[it] = xb + (size_t)tok * HID + (c_ ^ (rloc & 7)) * 8;
    }
    const unsigned short* bgsrc[2];
    const unsigned short* busrc[2];
#pragma unroll
    for (int it = 0; it < 2; it++) {
        int rloc = it * 32 + wave * 8 + r_;
        size_t boff = (size_t)e * INTER * HID + (size_t)(i0 + rloc) * HID + (c_ ^ (rloc & 7)) * 8;
        bgsrc[it] = wg_t + boff;
        busrc[it] = wu_t + boff;
    }

    f32x4 accg[4][2], accu[4][2];
#pragma unroll
    for (int mi = 0; mi < 4; mi++)
#pragma unroll
        for (int ni = 0; ni < 2; ni++) {
            accg[mi][ni] = {0.f, 0.f, 0.f, 0.f};
            accu[mi][ni] = {0.f, 0.f, 0.f, 0.f};
        }

    for (int k0 = 0; k0 < HID; k0 += 64) {
#pragma unroll
        for (int it = 0; it < 4; it++)
            gl2lds16(asrc[it] + k0, &As[(it * 32 + wave * 8) * 64]);
#pragma unroll
        for (int it = 0; it < 2; it++) {
            gl2lds16(bgsrc[it] + k0, &Bg[(it * 32 + wave * 8) * 64]);
            gl2lds16(busrc[it] + k0, &Bu[(it * 32 + wave * 8) * 64]);
        }
        __syncthreads();
#pragma unroll
        for (int kk8 = 0; kk8 < 8; kk8 += 4) {
            int q = kk8 + quad;
            int qs = (q ^ sw) * 8;
            bf16x8 a[4], bg[2], bu[2];
#pragma unroll
            for (int mi = 0; mi < 4; mi++)
                a[mi] = *(const bf16x8*)&As[(wm * 64 + mi * 16 + l16) * 64 + qs];
#pragma unroll
            for (int ni = 0; ni < 2; ni++) {
                bg[ni] = *(const bf16x8*)&Bg[(wn * 32 + ni * 16 + l16) * 64 + qs];
                bu[ni] = *(const bf16x8*)&Bu[(wn * 32 + ni * 16 + l16) * 64 + qs];
            }
#pragma unroll
            for (int mi = 0; mi < 4; mi++)
#pragma unroll
                for (int ni = 0; ni < 2; ni++) {
                    accg[mi][ni] = __builtin_amdgcn_mfma_f32_16x16x32_bf16(a[mi], bg[ni], accg[mi][ni], 0, 0, 0);
                    accu[mi][ni] = __builtin_amdgcn_mfma_f32_16x16x32_bf16(a[mi], bu[ni], accu[mi][ni], 0, 0, 0);
                }
        }
        __syncthreads();
    }
    // epilogue: silu(g)*u -> bf16  (C/D: col=lane&15, row=quad*4+reg)
#pragma unroll
    for (int mi = 0; mi < 4; mi++)
#pragma unroll
        for (int ni = 0; ni < 2; ni++)
#pragma unroll
            for (int r = 0; r < 4; r++) {
                int ml = wm * 64 + mi * 16 + quad * 4 + r;
                int row = row0 + ml;
                if (row < cnt) {
                    float g = accg[mi][ni][r], u = accu[mi][ni][r];
                    float hv = (g / (1.f + expf(-g))) * u;
                    h_buf[(size_t)(off + row) * INTER + i0 + wn * 32 + ni * 16 + l16] = f2bf(hv);
                }
            }
}

// ---------------------------------------------------------------- grouped GEMM2
// m97-style 128x128, per-wave 64x64, same XOR-swizzle staging.
__global__ __launch_bounds__(256) void moe_gemm2(
    const unsigned short* __restrict__ h_buf,  // [NROWS][INTER]
    const unsigned short* __restrict__ wd_t,   // [NE][HID][INTER]
    const int* __restrict__ offsets, const float* __restrict__ row_w,
    const int* __restrict__ wl,
    unsigned short* __restrict__ y_buf)        // [NROWS][HID]
{
    int wle = wl[blockIdx.y];
    int e = wle >> 24, row0 = wle & 0xffffff;
    int off = offsets[e], cnt = offsets[e + 1] - off;
    if (row0 >= cnt) return;
    int h0 = blockIdx.x * 128;

    __shared__ __align__(16) unsigned short As[128 * 64];  // 16 KB
    __shared__ __align__(16) unsigned short Bs[128 * 64];  // 16 KB

    int tid = threadIdx.x, wave = tid >> 6, lane = tid & 63;
    int wm = wave & 1, wn = wave >> 1;
    int l16 = lane & 15, quad = lane >> 4;
    int r_ = lane >> 3, c_ = lane & 7;
    int sw = l16 & 7;

    const unsigned short* asrc[4];
    const unsigned short* bsrc[4];
#pragma unroll
    for (int it = 0; it < 4; it++) {
        int rloc = it * 32 + wave * 8 + r_;
        int rg = row0 + rloc;
        asrc[it] = h_buf + (size_t)(off + ((rg < cnt) ? rg : 0)) * INTER + (c_ ^ (rloc & 7)) * 8;
        bsrc[it] = wd_t + (size_t)e * HID * INTER + (size_t)(h0 + rloc) * INTER + (c_ ^ (rloc & 7)) * 8;
    }

    f32x4 acc[4][4];
#pragma unroll
    for (int mi = 0; mi < 4; mi++)
#pragma unroll
        for (int ni = 0; ni < 4; ni++) acc[mi][ni] = {0.f, 0.f, 0.f, 0.f};

    for (int k0 = 0; k0 < INTER; k0 += 64) {
#pragma unroll
        for (int it = 0; it < 4; it++) {
            gl2lds16(asrc[it] + k0, &As[(it * 32 + wave * 8) * 64]);
            gl2lds16(bsrc[it] + k0, &Bs[(it * 32 + wave * 8) * 64]);
        }
        __syncthreads();
#pragma unroll
        for (int kk8 = 0; kk8 < 8; kk8 += 4) {
            int q = kk8 + quad;
            int qs = (q ^ sw) * 8;
            bf16x8 a[4], b[4];
#pragma unroll
            for (int mi = 0; mi < 4; mi++)
                a[mi] = *(const bf16x8*)&As[(wm * 64 + mi * 16 + l16) * 64 + qs];
#pragma unroll
            for (int ni = 0; ni < 4; ni++)
                b[ni] = *(const bf16x8*)&Bs[(wn * 64 + ni * 16 + l16) * 64 + qs];
#pragma unroll
            for (int mi = 0; mi < 4; mi++)
#pragma unroll
                for (int ni = 0; ni < 4; ni++)
                    acc[mi][ni] = __builtin_amdgcn_mfma_f32_16x16x32_bf16(a[mi], b[ni], acc[mi][ni], 0, 0, 0);
        }
        __syncthreads();
    }
#pragma unroll
    for (int mi = 0; mi < 4; mi++)
#pragma unroll
        for (int ni = 0; ni < 4; ni++)
#pragma unroll
            for (int r = 0; r < 4; r++) {
                int ml = wm * 64 + mi * 16 + quad * 4 + r;
                int row = row0 + ml;
                if (row < cnt) {
                    float w = row_w[off + row];
                    y_buf[(size_t)(off + row) * HID + h0 + wn * 64 + ni * 16 + l16] =
                        f2bf(acc[mi][ni][r] * w);
                }
            }
}

// ---------------------------------------------------------------- combine
__global__ __launch_bounds__(256) void moe_combine(
    const unsigned short* __restrict__ y_buf, const int* __restrict__ tok_rows,
    float* __restrict__ out)
{
    int gid = blockIdx.x * 256 + threadIdx.x;   // T*H/8 threads
    int t = gid >> 7;
    int c = gid & 127;
    u32x4 a = *(const u32x4*)(y_buf + (size_t)tok_rows[2 * t]     * HID + c * 8);
    u32x4 b = *(const u32x4*)(y_buf + (size_t)tok_rows[2 * t + 1] * HID + c * 8);
    float res[8];
#pragma unroll
    for (int j = 0; j < 4; j++) {
        unsigned int wa = a[j], wb = b[j];
        res[2 * j]     = __builtin_bit_cast(float, wa << 16)
                       + __builtin_bit_cast(float, wb << 16);
        res[2 * j + 1] = __builtin_bit_cast(float, wa & 0xffff0000u)
                       + __builtin_bit_cast(float, wb & 0xffff0000u);
    }
    float* o = out + (size_t)t * HID + c * 8;
    *(float4*)(o)     = make_float4(res[0], res[1], res[2], res[3]);
    *(float4*)(o + 4) = make_float4(res[4], res[5], res[6], res[7]);
}

// ---------------------------------------------------------------- launch
extern "C" void kernel_launch(void* const* d_in, const int* in_sizes, int n_in,
                              void* d_out, int out_size, void* d_ws, size_t ws_size,
                              hipStream_t stream)
{
    const float* x      = (const float*)d_in[0];
    const float* gate_w = (const float*)d_in[1];
    const float* w_gate = (const float*)d_in[2];
    const float* w_up   = (const float*)d_in[3];
    const float* w_down = (const float*)d_in[4];
    float* out = (float*)d_out;                    // final [T,H] ++ logits [T,E]
    float* logits_out = out + (size_t)T_TOK * HID;

    char* ws = (char*)d_ws;
    int*   offsets    = (int*)(ws + 0);                  // 9 ints
    int*   wl         = (int*)(ws + 128);                // MAXWL ints
    int*   hist_g     = (int*)(ws + 1024);               // RBLK*NE = 8 KB
    int*   topk_idx   = (int*)(ws + 32768);                       // 64 KB
    float* topk_w     = (float*)(ws + 32768 + 65536);             // 64 KB
    int*   row_token  = (int*)(ws + 32768 + 2 * 65536);           // 64 KB
    float* row_w      = (float*)(ws + 32768 + 3 * 65536);         // 64 KB
    int*   tok_rows   = (int*)(ws + 32768 + 4 * 65536);           // 64 KB
    size_t o = 32768 + 5 * (size_t)65536 + 32768;        // 393216
    unsigned short* xb   = (unsigned short*)(ws + o); o += (size_t)T_TOK * HID * 2;
    unsigned short* wg_t = (unsigned short*)(ws + o); o += (size_t)NE * INTER * HID * 2;
    unsigned short* wu_t = (unsigned short*)(ws + o); o += (size_t)NE * INTER * HID * 2;
    unsigned short* wd_t = (unsigned short*)(ws + o); o += (size_t)NE * HID * INTER * 2;
    unsigned short* h_buf = (unsigned short*)(ws + o); o += (size_t)NROWS * INTER * 2;
    unsigned short* y_buf = (unsigned short*)(ws + o); o += (size_t)NROWS * HID * 2;

    moe_prep<<<RBLK + 3 * TPM, 256, 0, stream>>>(
        x, gate_w, w_gate, w_up, w_down,
        xb, logits_out, topk_idx, topk_w, hist_g, wg_t, wu_t, wd_t);
    moe_scatter_scan<<<RBLK, 256, 0, stream>>>(
        hist_g, topk_idx, topk_w, offsets, wl, row_token, row_w, tok_rows);
    moe_gemm1<<<dim3(INTER / 64, MAXWL), 256, 0, stream>>>(
        xb, wg_t, wu_t, offsets, row_token, wl, h_buf);
    moe_gemm2<<<dim3(HID / 128, MAXWL), 256, 0, stream>>>(
        h_buf, wd_t, offsets, row_w, wl, y_buf);
    moe_combine<<<(T_TOK * HID / 8) / 256, 256, 0, stream>>>(y_buf, tok_rows, out);
}